// Round 14
// baseline (551.172 us; speedup 1.0000x reference)
//
#include <hip/hip_runtime.h>
#include <hip/hip_bf16.h>

#define B_ 4
#define N_ 4096
#define FIN 256
#define FOUT 128

typedef unsigned short u16;
typedef unsigned int u32;
typedef short bf16x8 __attribute__((ext_vector_type(8)));
typedef float f32x4 __attribute__((ext_vector_type(4)));
typedef int i32x4 __attribute__((ext_vector_type(4)));

__device__ __forceinline__ u16 f2bf(float x) {
  union { float f; unsigned int u; } v;
  v.f = x;
  unsigned int r = v.u + 0x7fffu + ((v.u >> 16) & 1u);  // RNE
  return (u16)(r >> 16);
}

__device__ __forceinline__ unsigned int pk2(float a, float b) {
  union { __hip_bfloat162 h2; unsigned int u; } v;
  v.h2 = __float22bfloat162_rn(make_float2(a, b));  // -> v_cvt_pk_bf16_f32
  return v.u;
}

// Kernel 1: Wh = h @ W (fp32 accum). Emits:
//  - f1[b][n] = Wh . a[:128], f2[b][n] = Wh . a[128:]   (fp32)
//  - WhT bf16 in MFMA-B tiled layout: whT[((b*512 + n/8)*128 + o)*8 + n%8]
__global__ __launch_bounds__(256) void wh_kernel(
    const float* __restrict__ h, const float* __restrict__ W,
    const float* __restrict__ a, u16* __restrict__ whT,
    float* __restrict__ f1, float* __restrict__ f2) {
  __shared__ float hs[16 * FIN];  // 16 KB
  const int tid = threadIdx.x;
  const int b = blockIdx.x >> 8;
  const int n0 = (blockIdx.x & 255) << 4;

  {
    const float4* src = (const float4*)(h + ((size_t)(b * N_ + n0)) * FIN);
    float4* dst = (float4*)hs;
#pragma unroll
    for (int i = 0; i < 4; ++i) dst[tid + i * 256] = src[tid + i * 256];
  }
  __syncthreads();

  const int o0 = (tid & 31) * 4;
  const int r0 = tid >> 5;
  float acc0[4] = {0.f, 0.f, 0.f, 0.f};
  float acc1[4] = {0.f, 0.f, 0.f, 0.f};
  const float* hr0 = hs + r0 * FIN;
  const float* hr1 = hs + (r0 + 8) * FIN;
#pragma unroll 4
  for (int k = 0; k < FIN; ++k) {
    const float4 w = *(const float4*)(W + k * FOUT + o0);
    const float h0 = hr0[k];
    const float h1 = hr1[k];
    acc0[0] = fmaf(h0, w.x, acc0[0]); acc0[1] = fmaf(h0, w.y, acc0[1]);
    acc0[2] = fmaf(h0, w.z, acc0[2]); acc0[3] = fmaf(h0, w.w, acc0[3]);
    acc1[0] = fmaf(h1, w.x, acc1[0]); acc1[1] = fmaf(h1, w.y, acc1[1]);
    acc1[2] = fmaf(h1, w.z, acc1[2]); acc1[3] = fmaf(h1, w.w, acc1[3]);
  }

  float s10 = 0.f, s11 = 0.f, s20 = 0.f, s21 = 0.f;
#pragma unroll
  for (int j = 0; j < 4; ++j) {
    const float a1v = a[o0 + j];
    const float a2v = a[FOUT + o0 + j];
    s10 = fmaf(acc0[j], a1v, s10); s20 = fmaf(acc0[j], a2v, s20);
    s11 = fmaf(acc1[j], a1v, s11); s21 = fmaf(acc1[j], a2v, s21);
  }
#pragma unroll
  for (int off = 16; off >= 1; off >>= 1) {
    s10 += __shfl_xor(s10, off); s11 += __shfl_xor(s11, off);
    s20 += __shfl_xor(s20, off); s21 += __shfl_xor(s21, off);
  }
  if ((tid & 31) == 0) {
    const int base = b * N_ + n0;
    f1[base + r0] = s10; f1[base + r0 + 8] = s11;
    f2[base + r0] = s20; f2[base + r0 + 8] = s21;
  }

  __syncthreads();
  u16* ts = (u16*)hs;  // [128 o][16 n]
#pragma unroll
  for (int j = 0; j < 4; ++j) {
    ts[(o0 + j) * 16 + r0]     = f2bf(acc0[j]);
    ts[(o0 + j) * 16 + r0 + 8] = f2bf(acc1[j]);
  }
  __syncthreads();
  const int o  = tid >> 1;
  const int hh = tid & 1;
  const uint4 vals = *(const uint4*)(ts + o * 16 + hh * 8);
  u16* dst = whT + ((size_t)((b * 512 + (n0 >> 3) + hh) * 128 + o)) * 8;
  *(uint4*)dst = vals;
}

// Kernel 2: bit-pack adj (values in {0,1}, semantic: >0) into u32 words.
// Word gid covers ints [gid*32, gid*32+32); bit i <- adj[gid*32+i] > 0.
__global__ __launch_bounds__(256) void pack_kernel(
    const int* __restrict__ adj, u32* __restrict__ pw) {
  const size_t gid = (size_t)blockIdx.x * 256 + threadIdx.x;
  const i32x4* src = (const i32x4*)(adj + gid * 32);
  u32 m = 0;
#pragma unroll
  for (int c = 0; c < 8; ++c) {
    const i32x4 v = __builtin_nontemporal_load(src + c);
    m |= (v[0] > 0 ? 1u : 0u) << (c * 4 + 0);
    m |= (v[1] > 0 ? 1u : 0u) << (c * 4 + 1);
    m |= (v[2] > 0 ? 1u : 0u) << (c * 4 + 2);
    m |= (v[3] > 0 ? 1u : 0u) << (c * 4 + 3);
  }
  pw[gid] = m;
}

__device__ __forceinline__ float pv2(u32 bit, float t) {
  const float e = fmaxf(t, 0.2f * t);  // leaky_relu slope 0.2
  const float ex = __expf(e);          // |e| <= ~7: no overflow, no max-shift needed
  return bit ? ex : 0.f;
}

// Kernel 3 (o-split): 16 rows/block, 4 waves; wave w owns output cols
// o in [32w, 32w+32) and walks the FULL j range (128 steps of K=32).
// Each wave redundantly computes p (masked exp) and its own denominator via
// a ones-B MFMA -> ZERO LDS, ZERO syncthreads, no cross-wave reduction,
// acc = 12 VGPR (vs 36), ~8 live fragment VGPR (vs 32). Low pressure, high
// occupancy; all inputs (mask 8.4MB, whT 1MB/batch, f2 64KB) L2-resident.
__global__ __launch_bounds__(256) void gat_kernel(
    const u32* __restrict__ pw, const u16* __restrict__ whT,
    const float* __restrict__ f1, const float* __restrict__ f2,
    float* __restrict__ out) {
  const int tid = threadIdx.x;
  const int w = tid >> 6;      // wave -> o chunk
  const int lane = tid & 63;
  const int b = blockIdx.x >> 8;
  const int i0 = (blockIdx.x & 255) << 4;
  const int row = lane & 15;
  const int kg = lane >> 4;
  const int ksh = kg << 3;

  const float f1r = f1[b * N_ + i0 + row];
  const u32* mp = pw + ((size_t)(b * N_ + i0 + row)) * 128;          // word s
  const float4* fq = (const float4*)(f2 + b * N_) + 2 * kg;          // +8/step
  const u16* wp = whT + ((size_t)((b * 512 + kg) * 128 + 32 * w + row)) * 8;

  f32x4 accA = (f32x4){0.f, 0.f, 0.f, 0.f};
  f32x4 accB = (f32x4){0.f, 0.f, 0.f, 0.f};
  f32x4 accD = (f32x4){0.f, 0.f, 0.f, 0.f};
  bf16x8 ones;
#pragma unroll
  for (int i = 0; i < 8; ++i) ones[i] = (short)0x3F80;  // bf16 1.0

#pragma unroll 2
  for (int s = 0; s < 128; ++s) {
    const bf16x8 bfA = *(const bf16x8*)(wp);        // o = 32w+row,    8 j
    const bf16x8 bfB = *(const bf16x8*)(wp + 128);  // o = 32w+16+row, 8 j
    const u32 mb = mp[s] >> ksh;                    // this lane's 8 mask bits
    const float4 fa = fq[0];
    const float4 fb = fq[1];
    const float p0 = pv2(mb & 1u,        f1r + fa.x);
    const float p1 = pv2((mb >> 1) & 1u, f1r + fa.y);
    const float p2 = pv2((mb >> 2) & 1u, f1r + fa.z);
    const float p3 = pv2((mb >> 3) & 1u, f1r + fa.w);
    const float p4 = pv2((mb >> 4) & 1u, f1r + fb.x);
    const float p5 = pv2((mb >> 5) & 1u, f1r + fb.y);
    const float p6 = pv2((mb >> 6) & 1u, f1r + fb.z);
    const float p7 = pv2((mb >> 7) & 1u, f1r + fb.w);
    union { bf16x8 v; unsigned int u[4]; } pf;
    pf.u[0] = pk2(p0, p1); pf.u[1] = pk2(p2, p3);
    pf.u[2] = pk2(p4, p5); pf.u[3] = pk2(p6, p7);
    accA = __builtin_amdgcn_mfma_f32_16x16x32_bf16(pf.v, bfA, accA, 0, 0, 0);
    accB = __builtin_amdgcn_mfma_f32_16x16x32_bf16(pf.v, bfB, accB, 0, 0, 0);
    accD = __builtin_amdgcn_mfma_f32_16x16x32_bf16(pf.v, ones, accD, 0, 0, 0);
    fq += 8;
    wp += 4096;
  }

  // Epilogue (wave-local): C/D layout row = (lane>>4)*4 + r, col = lane&15.
  // accD row r: all cols equal the row's full softmax denominator.
  const int orow = (lane >> 4) << 2;
  const int ocol = lane & 15;
  float* ob = out + ((size_t)(b * N_ + i0 + orow)) * FOUT + 32 * w + ocol;
#pragma unroll
  for (int r = 0; r < 4; ++r) {
    const float inv = 1.f / accD[r];
    const float xa = accA[r] * inv;
    const float xb = accB[r] * inv;
    ob[(size_t)r * FOUT]      = xa > 0.f ? xa : expm1f(xa);  // elu(alpha=1)
    ob[(size_t)r * FOUT + 16] = xb > 0.f ? xb : expm1f(xb);
  }
}

extern "C" void kernel_launch(void* const* d_in, const int* in_sizes, int n_in,
                              void* d_out, int out_size, void* d_ws, size_t ws_size,
                              hipStream_t stream) {
  const float* h = (const float*)d_in[0];
  const int* adj = (const int*)d_in[1];
  const float* W = (const float*)d_in[2];
  const float* a = (const float*)d_in[3];
  float* out = (float*)d_out;

  // ws layout: whT bf16 (4 MB) | f1 (64 KB) | f2 (64 KB) | pw bitmask (8.4 MB)
  char* wsb = (char*)d_ws;
  u16* whT = (u16*)wsb;
  float* f1 = (float*)(wsb + (size_t)B_ * FOUT * N_ * sizeof(u16));
  float* f2 = f1 + B_ * N_;
  u32* pw = (u32*)(wsb + (size_t)B_ * FOUT * N_ * sizeof(u16)
                   + 2 * (size_t)B_ * N_ * sizeof(float));

  pack_kernel<<<dim3(B_ * N_ * 128 / 256), dim3(256), 0, stream>>>(adj, pw);
  wh_kernel<<<dim3(B_ * (N_ / 16)), dim3(256), 0, stream>>>(h, W, a, whT, f1, f2);
  gat_kernel<<<dim3(B_ * (N_ / 16)), dim3(256), 0, stream>>>(pw, whT, f1, f2, out);
}